// Round 15
// baseline (332.546 us; speedup 1.0000x reference)
//
#include <hip/hip_runtime.h>
#include <cstdint>
#include <cstddef>

#define NB 32
#define NN 1024
#define ND 256
#define KNNK 16

typedef __attribute__((ext_vector_type(8))) short bf16x8;
typedef __attribute__((ext_vector_type(4))) float f32x4;

// Round-to-nearest-even bf16 split, packed as (hi<<16)|lo.
__device__ __forceinline__ uint32_t pack_bf16_split(float v) {
    uint32_t u  = __float_as_uint(v);
    uint32_t hi = (u + 0x7fffu + ((u >> 16) & 1u)) >> 16;
    float    hf = __uint_as_float(hi << 16);
    uint32_t g  = __float_as_uint(v - hf);
    uint32_t lo = (g + 0x7fffu + ((g >> 16) & 1u)) >> 16;
    return (hi << 16) | (lo & 0xffffu);
}

// ---------------------------------------------------------------------------
// Kernel A v15: fused pos-add + dual projection, packed bf16-split output.
// 32-row blocks (1024): H staged ONCE (H[256][36] = 36.9 KB; stride 36 keeps
// 16B alignment for b128 reads), e-loop = 4 tiles of 128 cols with
// Ws[16][132] (8.4 KB) chunk staging. LDS 45.3 KB -> 3 blocks/CU (12
// waves/CU) vs v14's 2 blocks/CU @ 74 KB (the occupancy regression).
// Per-element accumulation order identical to v13/v14 -> bit-identical
// Qp/Kp (absmax must stay exactly 0.01257324).
// ---------------------------------------------------------------------------
__global__ __launch_bounds__(256) void proj_kernel(
    const float* __restrict__ x, const float* __restrict__ pos,
    const float* __restrict__ wq, const float* __restrict__ bq,
    const float* __restrict__ wk, const float* __restrict__ bk,
    uint32_t* __restrict__ Qp, uint32_t* __restrict__ Kp)
{
    __shared__ __align__(16) float H[256][36];    // [d][row], 36.9 KB
    __shared__ __align__(16) float Ws[16][132];   // [d][e],   8.4 KB

    const int tid = threadIdx.x;
    const int tx = tid & 31;          // e microtile index (4*tx, 128 wide)
    const int ty = tid >> 5;          // row microtile index (4*ty, 32 rows)
    const int rowBase = (int)(blockIdx.x << 5);   // flattened b*1024 + n
    const int n0 = rowBase & 1023;

    // ---- stage H = x + pos, once: 32 rows x 32 d per pass, 8 passes ----
    {
        const int sr = tid >> 3;              // 0..31 row
        const int sd = (tid & 7) << 2;        // 0,4,..,28 d
        #pragma unroll 1
        for (int dc = 0; dc < 256; dc += 32) {
            const float4 xv = *(const float4*)&x[(size_t)(rowBase + sr) * 256 + dc + sd];
            const float4 pv = *(const float4*)&pos[(size_t)(n0 + sr) * 256 + dc + sd];
            H[dc + sd + 0][sr] = xv.x + pv.x;
            H[dc + sd + 1][sr] = xv.y + pv.y;
            H[dc + sd + 2][sr] = xv.z + pv.z;
            H[dc + sd + 3][sr] = xv.w + pv.w;
        }
    }
    // (first chunk's barrier below orders H writes before compute reads)

    const int sr2 = tid >> 1;             // 0..127 e (Ws staging)
    const int sd2 = (tid & 1) << 3;       // 0 or 8  d

    // ---- 4 e-tiles of 128: 0-1 -> Q (e0 0,128), 2-3 -> K ----
    #pragma unroll 1
    for (int et = 0; et < 4; ++et) {
        const bool isQ = (et < 2);
        const float* __restrict__ W    = isQ ? wq : wk;
        const float* __restrict__ bias = isQ ? bq : bk;
        uint32_t* __restrict__ Og      = isQ ? Qp : Kp;
        const int e0 = (et & 1) << 7;

        float acc[4][4];
        #pragma unroll
        for (int i = 0; i < 4; ++i)
            #pragma unroll
            for (int j = 0; j < 4; ++j) acc[i][j] = 0.0f;

        #pragma unroll 1
        for (int dc = 0; dc < 256; dc += 16) {
            const float4 wv0 = *(const float4*)&W[(size_t)(e0 + sr2) * 256 + dc + sd2];
            const float4 wv1 = *(const float4*)&W[(size_t)(e0 + sr2) * 256 + dc + sd2 + 4];
            __syncthreads();   // previous compute done reading Ws (and H writes)
            Ws[sd2 + 0][sr2] = wv0.x;
            Ws[sd2 + 1][sr2] = wv0.y;
            Ws[sd2 + 2][sr2] = wv0.z;
            Ws[sd2 + 3][sr2] = wv0.w;
            Ws[sd2 + 4][sr2] = wv1.x;
            Ws[sd2 + 5][sr2] = wv1.y;
            Ws[sd2 + 6][sr2] = wv1.z;
            Ws[sd2 + 7][sr2] = wv1.w;
            __syncthreads();
            #pragma unroll
            for (int d = 0; d < 16; ++d) {
                const float4 rv = *(const float4*)&H[dc + d][ty << 2];  // rows
                const float4 ev = *(const float4*)&Ws[d][tx << 2];      // cols
                const float a4[4] = {rv.x, rv.y, rv.z, rv.w};
                const float b4[4] = {ev.x, ev.y, ev.z, ev.w};
                #pragma unroll
                for (int i = 0; i < 4; ++i)
                    #pragma unroll
                    for (int j = 0; j < 4; ++j)
                        acc[i][j] = fmaf(a4[i], b4[j], acc[i][j]);
            }
        }

        const float4 bv4 = *(const float4*)&bias[e0 + (tx << 2)];
        const float bb[4] = {bv4.x, bv4.y, bv4.z, bv4.w};
        #pragma unroll
        for (int i = 0; i < 4; ++i)
            #pragma unroll
            for (int j = 0; j < 4; ++j) acc[i][j] += bb[j];

        #pragma unroll
        for (int i = 0; i < 4; ++i) {
            uint4 o;
            o.x = pack_bf16_split(acc[i][0]);
            o.y = pack_bf16_split(acc[i][1]);
            o.z = pack_bf16_split(acc[i][2]);
            o.w = pack_bf16_split(acc[i][3]);
            *(uint4*)&Og[(size_t)(rowBase + (ty << 2) + i) * 256 + e0 + (tx << 2)] = o;
        }
    }
}

// ---------------------------------------------------------------------------
// Kernel B1 (v13 verbatim): batched score GEMM via bf16-split MFMA.
// ---------------------------------------------------------------------------
__global__ __launch_bounds__(256, 4) void score_kernel(
    const uint32_t* __restrict__ Qp, const uint32_t* __restrict__ Kp,
    float* __restrict__ out)
{
    __shared__ __align__(16) uint32_t Ap[64][36];   // 9.2 KB (stride 36: 2-way)
    __shared__ __align__(16) uint32_t Bp[64][36];   // 9.2 KB

    const int tid  = threadIdx.x;
    const int lane = tid & 63;
    const int w    = tid >> 6;        // 0..3
    const int lr   = lane & 15;
    const int lh   = lane >> 4;
    const int bid  = ((blockIdx.x & 7) << 10) + (blockIdx.x >> 3);  // XCD swz
    const int b    = bid >> 8;
    const int tr   = (bid >> 4) & 15;
    const int tc   = bid & 15;

    const uint32_t* __restrict__ Abase = Qp + (size_t)((b << 10) + (tr << 6)) * 256;
    const uint32_t* __restrict__ Bbase = Kp + (size_t)((b << 10) + (tc << 6)) * 256;

    const int r0 = tid >> 3;          // 0..31 (staging row)
    const int g0 = tid & 7;           // 0..7  (staging 16B group)

    f32x4 acc[4];
    #pragma unroll
    for (int ct = 0; ct < 4; ++ct) acc[ct] = (f32x4){0.f, 0.f, 0.f, 0.f};

    // prologue: load chunk 0 staging regs
    uint4 sA0 = *(const uint4*)(Abase + (size_t)r0 * 256 + (g0 << 2));
    uint4 sA1 = *(const uint4*)(Abase + (size_t)(r0 + 32) * 256 + (g0 << 2));
    uint4 sB0 = *(const uint4*)(Bbase + (size_t)r0 * 256 + (g0 << 2));
    uint4 sB1 = *(const uint4*)(Bbase + (size_t)(r0 + 32) * 256 + (g0 << 2));

    #pragma unroll 1
    for (int c = 0; c < 8; ++c) {
        __syncthreads();              // previous chunk's LDS reads complete
        *(uint4*)&Ap[r0][g0 << 2]      = sA0;
        *(uint4*)&Ap[r0 + 32][g0 << 2] = sA1;
        *(uint4*)&Bp[r0][g0 << 2]      = sB0;
        *(uint4*)&Bp[r0 + 32][g0 << 2] = sB1;
        __syncthreads();

        if (c < 7) {                  // prefetch next chunk (overlaps compute)
            const size_t off = (size_t)((c + 1) << 5) + (g0 << 2);
            sA0 = *(const uint4*)(Abase + (size_t)r0 * 256 + off);
            sA1 = *(const uint4*)(Abase + (size_t)(r0 + 32) * 256 + off);
            sB0 = *(const uint4*)(Bbase + (size_t)r0 * 256 + off);
            sB1 = *(const uint4*)(Bbase + (size_t)(r0 + 32) * 256 + off);
        }

        // ---- A fragment (rows 16w+lr) ----
        const uint4 qa = *(const uint4*)&Ap[(w << 4) + lr][lh << 3];
        const uint4 qb = *(const uint4*)&Ap[(w << 4) + lr][(lh << 3) + 4];
        union { bf16x8 v; uint32_t u[4]; } qh, ql;
        qh.u[0] = __builtin_amdgcn_perm(qa.y, qa.x, 0x07060302u);
        ql.u[0] = __builtin_amdgcn_perm(qa.y, qa.x, 0x05040100u);
        qh.u[1] = __builtin_amdgcn_perm(qa.w, qa.z, 0x07060302u);
        ql.u[1] = __builtin_amdgcn_perm(qa.w, qa.z, 0x05040100u);
        qh.u[2] = __builtin_amdgcn_perm(qb.y, qb.x, 0x07060302u);
        ql.u[2] = __builtin_amdgcn_perm(qb.y, qb.x, 0x05040100u);
        qh.u[3] = __builtin_amdgcn_perm(qb.w, qb.z, 0x07060302u);
        ql.u[3] = __builtin_amdgcn_perm(qb.w, qb.z, 0x05040100u);

        #pragma unroll
        for (int ct = 0; ct < 4; ++ct) {
            const uint4 ka = *(const uint4*)&Bp[(ct << 4) + lr][lh << 3];
            const uint4 kb = *(const uint4*)&Bp[(ct << 4) + lr][(lh << 3) + 4];
            union { bf16x8 v; uint32_t u[4]; } kh, kl;
            kh.u[0] = __builtin_amdgcn_perm(ka.y, ka.x, 0x07060302u);
            kl.u[0] = __builtin_amdgcn_perm(ka.y, ka.x, 0x05040100u);
            kh.u[1] = __builtin_amdgcn_perm(ka.w, ka.z, 0x07060302u);
            kl.u[1] = __builtin_amdgcn_perm(ka.w, ka.z, 0x05040100u);
            kh.u[2] = __builtin_amdgcn_perm(kb.y, kb.x, 0x07060302u);
            kl.u[2] = __builtin_amdgcn_perm(kb.y, kb.x, 0x05040100u);
            kh.u[3] = __builtin_amdgcn_perm(kb.w, kb.z, 0x07060302u);
            kl.u[3] = __builtin_amdgcn_perm(kb.w, kb.z, 0x05040100u);

            acc[ct] = __builtin_amdgcn_mfma_f32_16x16x32_bf16(qh.v, kh.v, acc[ct], 0, 0, 0);
            acc[ct] = __builtin_amdgcn_mfma_f32_16x16x32_bf16(qh.v, kl.v, acc[ct], 0, 0, 0);
            acc[ct] = __builtin_amdgcn_mfma_f32_16x16x32_bf16(ql.v, kh.v, acc[ct], 0, 0, 0);
        }
    }

    // D layout (hw-verified): tile row = lh*4 + reg, tile col = lr.
    const int orow = (b << 10) + (tr << 6) + (w << 4) + (lh << 2);
    const int ocol = (tc << 6) + lr;
    #pragma unroll
    for (int ct = 0; ct < 4; ++ct) {
        float* op = out + (size_t)orow * 1024 + ocol + (ct << 4);
        op[0]                 = acc[ct].x;
        op[(size_t)1024]      = acc[ct].y;
        op[(size_t)2048]      = acc[ct].z;
        op[(size_t)3072]      = acc[ct].w;
    }
}

// ---------------------------------------------------------------------------
// Kernel B2 (v13 verbatim): softmax + top-16, in-place on out.
// ---------------------------------------------------------------------------
__global__ __launch_bounds__(256, 4) void topk_kernel(float* __restrict__ out)
{
    const int tid  = threadIdx.x;
    const int lane = tid & 63;
    const int w    = tid >> 6;
    const int rowBase = (int)(blockIdx.x << 3);

    float* __restrict__ r0p = out + (size_t)(rowBase + (w << 1) + 0) * 1024;
    float* __restrict__ r1p = out + (size_t)(rowBase + (w << 1) + 1) * 1024;

    float s0[16], s1[16];
    #pragma unroll
    for (int o = 0; o < 4; ++o) {
        const float4 a = *(const float4*)&r0p[(o << 8) + (lane << 2)];
        const float4 c = *(const float4*)&r1p[(o << 8) + (lane << 2)];
        s0[(o << 2) + 0] = a.x * 0.0625f;
        s0[(o << 2) + 1] = a.y * 0.0625f;
        s0[(o << 2) + 2] = a.z * 0.0625f;
        s0[(o << 2) + 3] = a.w * 0.0625f;
        s1[(o << 2) + 0] = c.x * 0.0625f;
        s1[(o << 2) + 1] = c.y * 0.0625f;
        s1[(o << 2) + 2] = c.z * 0.0625f;
        s1[(o << 2) + 3] = c.w * 0.0625f;
    }

    // row max (wave butterfly), both rows interleaved
    float mx0 = s0[0], mx1 = s1[0];
    #pragma unroll
    for (int i = 1; i < 16; ++i) {
        mx0 = fmaxf(mx0, s0[i]);
        mx1 = fmaxf(mx1, s1[i]);
    }
    #pragma unroll
    for (int off = 32; off > 0; off >>= 1) {
        mx0 = fmaxf(mx0, __shfl_xor(mx0, off));
        mx1 = fmaxf(mx1, __shfl_xor(mx1, off));
    }

    // softmax denominator
    float ls0 = 0.f, ls1 = 0.f;
    #pragma unroll
    for (int i = 0; i < 16; ++i) {
        ls0 += __expf(s0[i] - mx0);
        ls1 += __expf(s1[i] - mx1);
    }
    #pragma unroll
    for (int off = 32; off > 0; off >>= 1) {
        ls0 += __shfl_xor(ls0, off);
        ls1 += __shfl_xor(ls1, off);
    }
    const float rZ0 = 1.0f / ls0;
    const float rZ1 = 1.0f / ls1;

    // top-16 extraction on working copies; winners -> bitmasks
    float wv0[16], wv1[16];
    #pragma unroll
    for (int i = 0; i < 16; ++i) { wv0[i] = s0[i]; wv1[i] = s1[i]; }
    unsigned mask0 = 0u, mask1 = 0u;

    #pragma unroll 1
    for (int j = 0; j < KNNK; ++j) {
        float bv0 = wv0[0], bv1 = wv1[0];
        int   bi0 = 0,      bi1 = 0;
        #pragma unroll
        for (int i = 1; i < 16; ++i) {
            const bool c0 = wv0[i] > bv0;   // strict >, ascending slot scan
            bv0 = c0 ? wv0[i] : bv0;
            bi0 = c0 ? i      : bi0;
            const bool c1 = wv1[i] > bv1;
            bv1 = c1 ? wv1[i] : bv1;
            bi1 = c1 ? i      : bi1;
        }
        const int bm0 = ((bi0 >> 2) << 8) + (lane << 2) + (bi0 & 3);
        const int bm1 = ((bi1 >> 2) << 8) + (lane << 2) + (bi1 & 3);
        const unsigned ub0   = __float_as_uint(bv0);
        const unsigned ub1   = __float_as_uint(bv1);
        const unsigned mono0 = ub0 ^ (unsigned)(((int)ub0 >> 31) | 0x80000000);
        const unsigned mono1 = ub1 ^ (unsigned)(((int)ub1 >> 31) | 0x80000000);
        const unsigned long long key0 =
            ((unsigned long long)mono0 << 32) | (unsigned)(~bm0);
        const unsigned long long key1 =
            ((unsigned long long)mono1 << 32) | (unsigned)(~bm1);
        unsigned long long gk0 = key0, gk1 = key1;
        #pragma unroll
        for (int off = 32; off > 0; off >>= 1) {
            const unsigned long long o0 = __shfl_xor(gk0, off);
            const unsigned long long o1 = __shfl_xor(gk1, off);
            gk0 = (o0 > gk0) ? o0 : gk0;
            gk1 = (o1 > gk1) ? o1 : gk1;
        }
        if (key0 == gk0) {               // unique winner lane, row 0
            mask0 |= (1u << bi0);
            #pragma unroll
            for (int i = 0; i < 16; ++i)
                wv0[i] = (i == bi0) ? -__builtin_inff() : wv0[i];
        }
        if (key1 == gk1) {               // unique winner lane, row 1
            mask1 |= (1u << bi1);
            #pragma unroll
            for (int i = 0; i < 16; ++i)
                wv1[i] = (i == bi1) ? -__builtin_inff() : wv1[i];
        }
    }

    // full-coverage coalesced writes from pristine s0/s1
    #pragma unroll
    for (int o = 0; o < 4; ++o) {
        float4 v;
        v.x = ((mask0 >> ((o << 2) + 0)) & 1u) ? __expf(s0[(o << 2) + 0] - mx0) * rZ0 : 0.f;
        v.y = ((mask0 >> ((o << 2) + 1)) & 1u) ? __expf(s0[(o << 2) + 1] - mx0) * rZ0 : 0.f;
        v.z = ((mask0 >> ((o << 2) + 2)) & 1u) ? __expf(s0[(o << 2) + 2] - mx0) * rZ0 : 0.f;
        v.w = ((mask0 >> ((o << 2) + 3)) & 1u) ? __expf(s0[(o << 2) + 3] - mx0) * rZ0 : 0.f;
        *(float4*)&r0p[(lane << 2) + (o << 8)] = v;
    }
    #pragma unroll
    for (int o = 0; o < 4; ++o) {
        float4 v;
        v.x = ((mask1 >> ((o << 2) + 0)) & 1u) ? __expf(s1[(o << 2) + 0] - mx1) * rZ1 : 0.f;
        v.y = ((mask1 >> ((o << 2) + 1)) & 1u) ? __expf(s1[(o << 2) + 1] - mx1) * rZ1 : 0.f;
        v.z = ((mask1 >> ((o << 2) + 2)) & 1u) ? __expf(s1[(o << 2) + 2] - mx1) * rZ1 : 0.f;
        v.w = ((mask1 >> ((o << 2) + 3)) & 1u) ? __expf(s1[(o << 2) + 3] - mx1) * rZ1 : 0.f;
        *(float4*)&r1p[(lane << 2) + (o << 8)] = v;
    }
}

extern "C" void kernel_launch(void* const* d_in, const int* in_sizes, int n_in,
                              void* d_out, int out_size, void* d_ws, size_t ws_size,
                              hipStream_t stream)
{
    const float* x   = (const float*)d_in[0];
    const float* pos = (const float*)d_in[1];
    const float* wq  = (const float*)d_in[2];
    const float* bq  = (const float*)d_in[3];
    const float* wk  = (const float*)d_in[4];
    const float* bk  = (const float*)d_in[5];
    float* out = (float*)d_out;

    uint32_t* Qp = (uint32_t*)d_ws;                  // 32 MiB packed bf16-split
    uint32_t* Kp = Qp + (size_t)NB * NN * ND;        // 32 MiB packed bf16-split

    proj_kernel<<<dim3(1024), dim3(256), 0, stream>>>(x, pos, wq, bq, wk, bk, Qp, Kp);
    score_kernel<<<dim3(8192), dim3(256), 0, stream>>>(Qp, Kp, out);
    topk_kernel<<<dim3(4096), dim3(256), 0, stream>>>(out);
}

// Round 16
// 294.415 us; speedup vs baseline: 1.1295x; 1.1295x over previous
//
#include <hip/hip_runtime.h>
#include <cstdint>
#include <cstddef>

#define NB 32
#define NN 1024
#define ND 256
#define KNNK 16

typedef __attribute__((ext_vector_type(8))) short bf16x8;
typedef __attribute__((ext_vector_type(4))) float f32x4;

// Round-to-nearest-even bf16 split, packed as (hi<<16)|lo.
__device__ __forceinline__ uint32_t pack_bf16_split(float v) {
    uint32_t u  = __float_as_uint(v);
    uint32_t hi = (u + 0x7fffu + ((u >> 16) & 1u)) >> 16;
    float    hf = __uint_as_float(hi << 16);
    uint32_t g  = __float_as_uint(v - hf);
    uint32_t lo = (g + 0x7fffu + ((g >> 16) & 1u)) >> 16;
    return (hi << 16) | (lo & 0xffffu);
}

// ---------------------------------------------------------------------------
// Kernel A v16: fused pos-add + dual projection, packed bf16-split output.
// Back to v13's winning structure (64-row x 64-e tiles, small LDS, 63% occ),
// with two fixes isolated from v13's counters:
//  1. LDS stride 64 -> 68: staging writes/reads become <=2-way (free),
//     killing v13's 1.26e7 SQ_LDS_BANK_CONFLICT (~20 us).
//  2. Q and K merged per block (grid 2048): H staged once per chunk feeds
//     BOTH accQ and accK -> x/pos fetched 4x instead of 8x (FETCH 152->~80MB)
//     and H-staging VALU halved; inner loop has 2x FMA ILP.
// Per-output accumulation order identical to v13 -> bit-identical Qp/Kp
// (absmax must stay exactly 0.01257324).
// ---------------------------------------------------------------------------
__global__ __launch_bounds__(256) void proj_kernel(
    const float* __restrict__ x, const float* __restrict__ pos,
    const float* __restrict__ wq, const float* __restrict__ bq,
    const float* __restrict__ wk, const float* __restrict__ bk,
    uint32_t* __restrict__ Qp, uint32_t* __restrict__ Kp)
{
    __shared__ __align__(16) float Hs [16][68];   // [d][row_local], 4.25 KB
    __shared__ __align__(16) float WsQ[16][68];   // [d][e_local]
    __shared__ __align__(16) float WsK[16][68];   // [d][e_local]

    const int tid = threadIdx.x;
    const int tx = tid & 15;          // e microtile index
    const int ty = tid >> 4;          // row microtile index
    const int bm = blockIdx.x >> 2;   // 0..511 row tiles
    const int be = blockIdx.x & 3;    // 0..3 e tiles (both Q and K)
    const int rowBase = bm << 6;      // flattened b*1024 + n
    const int n0 = rowBase & 1023;
    const int e0 = be << 6;

    const int sr = tid >> 2;          // 0..63 (row or e index for staging)
    const int sd = (tid & 3) << 2;    // 0,4,8,12

    float accQ[4][4], accK[4][4];
    #pragma unroll
    for (int i = 0; i < 4; ++i)
        #pragma unroll
        for (int j = 0; j < 4; ++j) { accQ[i][j] = 0.0f; accK[i][j] = 0.0f; }

    #pragma unroll 1
    for (int dc = 0; dc < 256; dc += 16) {
        const float4 xv  = *(const float4*)&x  [(size_t)(rowBase + sr) * 256 + dc + sd];
        const float4 pv  = *(const float4*)&pos[(size_t)(n0 + sr) * 256 + dc + sd];
        const float4 wqv = *(const float4*)&wq [(size_t)(e0 + sr) * 256 + dc + sd];
        const float4 wkv = *(const float4*)&wk [(size_t)(e0 + sr) * 256 + dc + sd];
        __syncthreads();   // previous compute done reading LDS
        Hs [sd + 0][sr] = xv.x + pv.x;
        Hs [sd + 1][sr] = xv.y + pv.y;
        Hs [sd + 2][sr] = xv.z + pv.z;
        Hs [sd + 3][sr] = xv.w + pv.w;
        WsQ[sd + 0][sr] = wqv.x;
        WsQ[sd + 1][sr] = wqv.y;
        WsQ[sd + 2][sr] = wqv.z;
        WsQ[sd + 3][sr] = wqv.w;
        WsK[sd + 0][sr] = wkv.x;
        WsK[sd + 1][sr] = wkv.y;
        WsK[sd + 2][sr] = wkv.z;
        WsK[sd + 3][sr] = wkv.w;
        __syncthreads();
        #pragma unroll
        for (int d = 0; d < 16; ++d) {
            const float4 rv = *(const float4*)&Hs [d][ty << 2];   // rows (n)
            const float4 eq = *(const float4*)&WsQ[d][tx << 2];   // Q cols (e)
            const float4 ek = *(const float4*)&WsK[d][tx << 2];   // K cols (e)
            const float a4[4] = {rv.x, rv.y, rv.z, rv.w};
            const float q4[4] = {eq.x, eq.y, eq.z, eq.w};
            const float k4[4] = {ek.x, ek.y, ek.z, ek.w};
            #pragma unroll
            for (int i = 0; i < 4; ++i)
                #pragma unroll
                for (int j = 0; j < 4; ++j) {
                    accQ[i][j] = fmaf(a4[i], q4[j], accQ[i][j]);
                    accK[i][j] = fmaf(a4[i], k4[j], accK[i][j]);
                }
        }
    }

    const float4 bq4 = *(const float4*)&bq[e0 + (tx << 2)];
    const float4 bk4 = *(const float4*)&bk[e0 + (tx << 2)];
    const float bbq[4] = {bq4.x, bq4.y, bq4.z, bq4.w};
    const float bbk[4] = {bk4.x, bk4.y, bk4.z, bk4.w};
    #pragma unroll
    for (int i = 0; i < 4; ++i)
        #pragma unroll
        for (int j = 0; j < 4; ++j) {
            accQ[i][j] += bbq[j];
            accK[i][j] += bbk[j];
        }

    #pragma unroll
    for (int i = 0; i < 4; ++i) {
        uint4 oq, ok;
        oq.x = pack_bf16_split(accQ[i][0]);
        oq.y = pack_bf16_split(accQ[i][1]);
        oq.z = pack_bf16_split(accQ[i][2]);
        oq.w = pack_bf16_split(accQ[i][3]);
        ok.x = pack_bf16_split(accK[i][0]);
        ok.y = pack_bf16_split(accK[i][1]);
        ok.z = pack_bf16_split(accK[i][2]);
        ok.w = pack_bf16_split(accK[i][3]);
        *(uint4*)&Qp[(size_t)(rowBase + (ty << 2) + i) * 256 + e0 + (tx << 2)] = oq;
        *(uint4*)&Kp[(size_t)(rowBase + (ty << 2) + i) * 256 + e0 + (tx << 2)] = ok;
    }
}

// ---------------------------------------------------------------------------
// Kernel B1 (v13 verbatim): batched score GEMM via bf16-split MFMA.
// ---------------------------------------------------------------------------
__global__ __launch_bounds__(256, 4) void score_kernel(
    const uint32_t* __restrict__ Qp, const uint32_t* __restrict__ Kp,
    float* __restrict__ out)
{
    __shared__ __align__(16) uint32_t Ap[64][36];   // 9.2 KB (stride 36: 2-way)
    __shared__ __align__(16) uint32_t Bp[64][36];   // 9.2 KB

    const int tid  = threadIdx.x;
    const int lane = tid & 63;
    const int w    = tid >> 6;        // 0..3
    const int lr   = lane & 15;
    const int lh   = lane >> 4;
    const int bid  = ((blockIdx.x & 7) << 10) + (blockIdx.x >> 3);  // XCD swz
    const int b    = bid >> 8;
    const int tr   = (bid >> 4) & 15;
    const int tc   = bid & 15;

    const uint32_t* __restrict__ Abase = Qp + (size_t)((b << 10) + (tr << 6)) * 256;
    const uint32_t* __restrict__ Bbase = Kp + (size_t)((b << 10) + (tc << 6)) * 256;

    const int r0 = tid >> 3;          // 0..31 (staging row)
    const int g0 = tid & 7;           // 0..7  (staging 16B group)

    f32x4 acc[4];
    #pragma unroll
    for (int ct = 0; ct < 4; ++ct) acc[ct] = (f32x4){0.f, 0.f, 0.f, 0.f};

    // prologue: load chunk 0 staging regs
    uint4 sA0 = *(const uint4*)(Abase + (size_t)r0 * 256 + (g0 << 2));
    uint4 sA1 = *(const uint4*)(Abase + (size_t)(r0 + 32) * 256 + (g0 << 2));
    uint4 sB0 = *(const uint4*)(Bbase + (size_t)r0 * 256 + (g0 << 2));
    uint4 sB1 = *(const uint4*)(Bbase + (size_t)(r0 + 32) * 256 + (g0 << 2));

    #pragma unroll 1
    for (int c = 0; c < 8; ++c) {
        __syncthreads();              // previous chunk's LDS reads complete
        *(uint4*)&Ap[r0][g0 << 2]      = sA0;
        *(uint4*)&Ap[r0 + 32][g0 << 2] = sA1;
        *(uint4*)&Bp[r0][g0 << 2]      = sB0;
        *(uint4*)&Bp[r0 + 32][g0 << 2] = sB1;
        __syncthreads();

        if (c < 7) {                  // prefetch next chunk (overlaps compute)
            const size_t off = (size_t)((c + 1) << 5) + (g0 << 2);
            sA0 = *(const uint4*)(Abase + (size_t)r0 * 256 + off);
            sA1 = *(const uint4*)(Abase + (size_t)(r0 + 32) * 256 + off);
            sB0 = *(const uint4*)(Bbase + (size_t)r0 * 256 + off);
            sB1 = *(const uint4*)(Bbase + (size_t)(r0 + 32) * 256 + off);
        }

        // ---- A fragment (rows 16w+lr) ----
        const uint4 qa = *(const uint4*)&Ap[(w << 4) + lr][lh << 3];
        const uint4 qb = *(const uint4*)&Ap[(w << 4) + lr][(lh << 3) + 4];
        union { bf16x8 v; uint32_t u[4]; } qh, ql;
        qh.u[0] = __builtin_amdgcn_perm(qa.y, qa.x, 0x07060302u);
        ql.u[0] = __builtin_amdgcn_perm(qa.y, qa.x, 0x05040100u);
        qh.u[1] = __builtin_amdgcn_perm(qa.w, qa.z, 0x07060302u);
        ql.u[1] = __builtin_amdgcn_perm(qa.w, qa.z, 0x05040100u);
        qh.u[2] = __builtin_amdgcn_perm(qb.y, qb.x, 0x07060302u);
        ql.u[2] = __builtin_amdgcn_perm(qb.y, qb.x, 0x05040100u);
        qh.u[3] = __builtin_amdgcn_perm(qb.w, qb.z, 0x07060302u);
        ql.u[3] = __builtin_amdgcn_perm(qb.w, qb.z, 0x05040100u);

        #pragma unroll
        for (int ct = 0; ct < 4; ++ct) {
            const uint4 ka = *(const uint4*)&Bp[(ct << 4) + lr][lh << 3];
            const uint4 kb = *(const uint4*)&Bp[(ct << 4) + lr][(lh << 3) + 4];
            union { bf16x8 v; uint32_t u[4]; } kh, kl;
            kh.u[0] = __builtin_amdgcn_perm(ka.y, ka.x, 0x07060302u);
            kl.u[0] = __builtin_amdgcn_perm(ka.y, ka.x, 0x05040100u);
            kh.u[1] = __builtin_amdgcn_perm(ka.w, ka.z, 0x07060302u);
            kl.u[1] = __builtin_amdgcn_perm(ka.w, ka.z, 0x05040100u);
            kh.u[2] = __builtin_amdgcn_perm(kb.y, kb.x, 0x07060302u);
            kl.u[2] = __builtin_amdgcn_perm(kb.y, kb.x, 0x05040100u);
            kh.u[3] = __builtin_amdgcn_perm(kb.w, kb.z, 0x07060302u);
            kl.u[3] = __builtin_amdgcn_perm(kb.w, kb.z, 0x05040100u);

            acc[ct] = __builtin_amdgcn_mfma_f32_16x16x32_bf16(qh.v, kh.v, acc[ct], 0, 0, 0);
            acc[ct] = __builtin_amdgcn_mfma_f32_16x16x32_bf16(qh.v, kl.v, acc[ct], 0, 0, 0);
            acc[ct] = __builtin_amdgcn_mfma_f32_16x16x32_bf16(ql.v, kh.v, acc[ct], 0, 0, 0);
        }
    }

    // D layout (hw-verified): tile row = lh*4 + reg, tile col = lr.
    const int orow = (b << 10) + (tr << 6) + (w << 4) + (lh << 2);
    const int ocol = (tc << 6) + lr;
    #pragma unroll
    for (int ct = 0; ct < 4; ++ct) {
        float* op = out + (size_t)orow * 1024 + ocol + (ct << 4);
        op[0]                 = acc[ct].x;
        op[(size_t)1024]      = acc[ct].y;
        op[(size_t)2048]      = acc[ct].z;
        op[(size_t)3072]      = acc[ct].w;
    }
}

// ---------------------------------------------------------------------------
// Kernel B2 (v13 verbatim): softmax + top-16, in-place on out.
// ---------------------------------------------------------------------------
__global__ __launch_bounds__(256, 4) void topk_kernel(float* __restrict__ out)
{
    const int tid  = threadIdx.x;
    const int lane = tid & 63;
    const int w    = tid >> 6;
    const int rowBase = (int)(blockIdx.x << 3);

    float* __restrict__ r0p = out + (size_t)(rowBase + (w << 1) + 0) * 1024;
    float* __restrict__ r1p = out + (size_t)(rowBase + (w << 1) + 1) * 1024;

    float s0[16], s1[16];
    #pragma unroll
    for (int o = 0; o < 4; ++o) {
        const float4 a = *(const float4*)&r0p[(o << 8) + (lane << 2)];
        const float4 c = *(const float4*)&r1p[(o << 8) + (lane << 2)];
        s0[(o << 2) + 0] = a.x * 0.0625f;
        s0[(o << 2) + 1] = a.y * 0.0625f;
        s0[(o << 2) + 2] = a.z * 0.0625f;
        s0[(o << 2) + 3] = a.w * 0.0625f;
        s1[(o << 2) + 0] = c.x * 0.0625f;
        s1[(o << 2) + 1] = c.y * 0.0625f;
        s1[(o << 2) + 2] = c.z * 0.0625f;
        s1[(o << 2) + 3] = c.w * 0.0625f;
    }

    // row max (wave butterfly), both rows interleaved
    float mx0 = s0[0], mx1 = s1[0];
    #pragma unroll
    for (int i = 1; i < 16; ++i) {
        mx0 = fmaxf(mx0, s0[i]);
        mx1 = fmaxf(mx1, s1[i]);
    }
    #pragma unroll
    for (int off = 32; off > 0; off >>= 1) {
        mx0 = fmaxf(mx0, __shfl_xor(mx0, off));
        mx1 = fmaxf(mx1, __shfl_xor(mx1, off));
    }

    // softmax denominator
    float ls0 = 0.f, ls1 = 0.f;
    #pragma unroll
    for (int i = 0; i < 16; ++i) {
        ls0 += __expf(s0[i] - mx0);
        ls1 += __expf(s1[i] - mx1);
    }
    #pragma unroll
    for (int off = 32; off > 0; off >>= 1) {
        ls0 += __shfl_xor(ls0, off);
        ls1 += __shfl_xor(ls1, off);
    }
    const float rZ0 = 1.0f / ls0;
    const float rZ1 = 1.0f / ls1;

    // top-16 extraction on working copies; winners -> bitmasks
    float wv0[16], wv1[16];
    #pragma unroll
    for (int i = 0; i < 16; ++i) { wv0[i] = s0[i]; wv1[i] = s1[i]; }
    unsigned mask0 = 0u, mask1 = 0u;

    #pragma unroll 1
    for (int j = 0; j < KNNK; ++j) {
        float bv0 = wv0[0], bv1 = wv1[0];
        int   bi0 = 0,      bi1 = 0;
        #pragma unroll
        for (int i = 1; i < 16; ++i) {
            const bool c0 = wv0[i] > bv0;   // strict >, ascending slot scan
            bv0 = c0 ? wv0[i] : bv0;
            bi0 = c0 ? i      : bi0;
            const bool c1 = wv1[i] > bv1;
            bv1 = c1 ? wv1[i] : bv1;
            bi1 = c1 ? i      : bi1;
        }
        const int bm0 = ((bi0 >> 2) << 8) + (lane << 2) + (bi0 & 3);
        const int bm1 = ((bi1 >> 2) << 8) + (lane << 2) + (bi1 & 3);
        const unsigned ub0   = __float_as_uint(bv0);
        const unsigned ub1   = __float_as_uint(bv1);
        const unsigned mono0 = ub0 ^ (unsigned)(((int)ub0 >> 31) | 0x80000000);
        const unsigned mono1 = ub1 ^ (unsigned)(((int)ub1 >> 31) | 0x80000000);
        const unsigned long long key0 =
            ((unsigned long long)mono0 << 32) | (unsigned)(~bm0);
        const unsigned long long key1 =
            ((unsigned long long)mono1 << 32) | (unsigned)(~bm1);
        unsigned long long gk0 = key0, gk1 = key1;
        #pragma unroll
        for (int off = 32; off > 0; off >>= 1) {
            const unsigned long long o0 = __shfl_xor(gk0, off);
            const unsigned long long o1 = __shfl_xor(gk1, off);
            gk0 = (o0 > gk0) ? o0 : gk0;
            gk1 = (o1 > gk1) ? o1 : gk1;
        }
        if (key0 == gk0) {               // unique winner lane, row 0
            mask0 |= (1u << bi0);
            #pragma unroll
            for (int i = 0; i < 16; ++i)
                wv0[i] = (i == bi0) ? -__builtin_inff() : wv0[i];
        }
        if (key1 == gk1) {               // unique winner lane, row 1
            mask1 |= (1u << bi1);
            #pragma unroll
            for (int i = 0; i < 16; ++i)
                wv1[i] = (i == bi1) ? -__builtin_inff() : wv1[i];
        }
    }

    // full-coverage coalesced writes from pristine s0/s1
    #pragma unroll
    for (int o = 0; o < 4; ++o) {
        float4 v;
        v.x = ((mask0 >> ((o << 2) + 0)) & 1u) ? __expf(s0[(o << 2) + 0] - mx0) * rZ0 : 0.f;
        v.y = ((mask0 >> ((o << 2) + 1)) & 1u) ? __expf(s0[(o << 2) + 1] - mx0) * rZ0 : 0.f;
        v.z = ((mask0 >> ((o << 2) + 2)) & 1u) ? __expf(s0[(o << 2) + 2] - mx0) * rZ0 : 0.f;
        v.w = ((mask0 >> ((o << 2) + 3)) & 1u) ? __expf(s0[(o << 2) + 3] - mx0) * rZ0 : 0.f;
        *(float4*)&r0p[(lane << 2) + (o << 8)] = v;
    }
    #pragma unroll
    for (int o = 0; o < 4; ++o) {
        float4 v;
        v.x = ((mask1 >> ((o << 2) + 0)) & 1u) ? __expf(s1[(o << 2) + 0] - mx1) * rZ1 : 0.f;
        v.y = ((mask1 >> ((o << 2) + 1)) & 1u) ? __expf(s1[(o << 2) + 1] - mx1) * rZ1 : 0.f;
        v.z = ((mask1 >> ((o << 2) + 2)) & 1u) ? __expf(s1[(o << 2) + 2] - mx1) * rZ1 : 0.f;
        v.w = ((mask1 >> ((o << 2) + 3)) & 1u) ? __expf(s1[(o << 2) + 3] - mx1) * rZ1 : 0.f;
        *(float4*)&r1p[(lane << 2) + (o << 8)] = v;
    }
}

extern "C" void kernel_launch(void* const* d_in, const int* in_sizes, int n_in,
                              void* d_out, int out_size, void* d_ws, size_t ws_size,
                              hipStream_t stream)
{
    const float* x   = (const float*)d_in[0];
    const float* pos = (const float*)d_in[1];
    const float* wq  = (const float*)d_in[2];
    const float* bq  = (const float*)d_in[3];
    const float* wk  = (const float*)d_in[4];
    const float* bk  = (const float*)d_in[5];
    float* out = (float*)d_out;

    uint32_t* Qp = (uint32_t*)d_ws;                  // 32 MiB packed bf16-split
    uint32_t* Kp = Qp + (size_t)NB * NN * ND;        // 32 MiB packed bf16-split

    proj_kernel<<<dim3(2048), dim3(256), 0, stream>>>(x, pos, wq, bq, wk, bk, Qp, Kp);
    score_kernel<<<dim3(8192), dim3(256), 0, stream>>>(Qp, Kp, out);
    topk_kernel<<<dim3(4096), dim3(256), 0, stream>>>(out);
}